// Round 5
// baseline (230.869 us; speedup 1.0000x reference)
//
#include <hip/hip_runtime.h>

// diff_lpc2rc: per-row backward Levinson recursion on N=16 fp32 values.
// Rows: 64 * 32768 = 2,097,152. ~268 MB HBM traffic; copy-ceiling ~43 us.
//
// R6: per-wave software pipelining. Evidence: three structurally different
// kernels (LDS+full-math, LDS+deferred, DPP+deferred) all landed ~77-80us
// ~= VALU(36us) + mem(43us) with no overlap - each wave was a one-shot
// load -> wait -> 700cy dependent compute -> store. Now each wave owns
// TILES_PER_WAVE=4 consecutive 64-row tiles and prefetches tile t+1's
// loads into the just-freed ld registers right after tile t's input
// transpose, so HBM latency hides under recursion + inverse transpose +
// store (~500-600 cy) plus TLP. Grid 8192 -> 2048 blocks, still 8
// blocks/CU (32 waves/CU).
//
// Kept from R5c (verified passing): DPP quad_perm butterfly transpose
// (all DPP unconditional - convergent op must see full exec; selection
// via value-selects only), deferred-scale recursion, plain f32x4 stores.

constexpr int N = 16;
constexpr int WAVES_PER_WG = 4;     // 256 threads
constexpr int TILES_PER_WAVE = 4;   // 64-row tiles per wave, pipelined

typedef float f32x4 __attribute__((ext_vector_type(4)));

__device__ __forceinline__ float dpp_xor2(float x) {
    // quad_perm [2,3,0,1] = 0x4E : lane q reads lane q^2 within its quad
    const int xi = __float_as_int(x);
    return __int_as_float(__builtin_amdgcn_update_dpp(xi, xi, 0x4E, 0xF, 0xF, true));
}
__device__ __forceinline__ float dpp_xor1(float x) {
    // quad_perm [1,0,3,2] = 0xB1 : lane q reads lane q^1 within its quad
    const int xi = __float_as_int(x);
    return __int_as_float(__builtin_amdgcn_update_dpp(xi, xi, 0xB1, 0xF, 0xF, true));
}

__device__ __forceinline__ void levinson16(float a[N]) {
    // deferred-scale backward Levinson: single fma per element per step;
    // one shared scalar inv_s accumulates the 1/(1-k^2) product.
    float inv_s = 1.0f;
#pragma unroll
    for (int i = 1; i < N; ++i) {
        const int len = N - i;
        const float k = a[len] * inv_s;      // true reflection coeff = final out[len]
        a[len] = k;
        const float r = __builtin_amdgcn_rcpf(1.0f - k * k);
        inv_s *= r;
#pragma unroll
        for (int m = 0; m < len / 2; ++m) {
            const int j = len - 1 - m;
            const float am = a[m];
            const float aj = a[j];
            a[m] = __builtin_fmaf(-k, aj, am);
            a[j] = __builtin_fmaf(-k, am, aj);
        }
        if (len & 1) {
            const int mid = len / 2;
            const float t = a[mid];
            a[mid] = __builtin_fmaf(-k, t, t);
        }
    }
    a[0] *= inv_s;
}

__global__ __launch_bounds__(256, 8) void lpc2rc_kernel(const float* __restrict__ x,
                                                        float* __restrict__ out,
                                                        int nrows) {
    const int tid  = threadIdx.x;
    const int lane = tid & 63;
    const bool hi = (lane >> 1) & 1;   // bit1 of quad index
    const bool lo = lane & 1;          // bit0 of quad index

    const f32x4* __restrict__ in4 = (const f32x4*)x;
    f32x4* __restrict__ out4 = (f32x4*)out;

    const long long tile0 =
        ((long long)blockIdx.x * WAVES_PER_WG + (tid >> 6)) * TILES_PER_WAVE;

    float a[N];
    float W[4][4];
    f32x4 ld[4];

    // ---- prologue: load first tile if full ----
    {
        const long long r0 = tile0 * 64;
        if (r0 + 64 <= (long long)nrows) {
            const long long b4 = r0 * 4;
#pragma unroll
            for (int c = 0; c < 4; ++c)
                ld[c] = in4[b4 + (long long)(c * 64 + lane)];
        }
    }

#pragma unroll
    for (int t = 0; t < TILES_PER_WAVE; ++t) {
        const long long r0 = (tile0 + t) * 64;
        if (r0 >= (long long)nrows) return;            // wave-uniform

        if (r0 + 64 <= (long long)nrows) {
            // ---- full tile: quad transpose in (lane 4g+q -> row 16q+g) ----
#pragma unroll
            for (int e = 0; e < 4; ++e) {
                const float x0 = dpp_xor2(ld[0][e]);
                const float x1 = dpp_xor2(ld[1][e]);
                const float x2 = dpp_xor2(ld[2][e]);
                const float x3 = dpp_xor2(ld[3][e]);
                W[0][e] = hi ? x2 : ld[0][e];
                W[1][e] = hi ? x3 : ld[1][e];
                W[2][e] = hi ? ld[2][e] : x0;
                W[3][e] = hi ? ld[3][e] : x1;
            }
#pragma unroll
            for (int e = 0; e < 4; ++e) {
                const float y0 = dpp_xor1(W[0][e]);
                const float y1 = dpp_xor1(W[1][e]);
                const float y2 = dpp_xor1(W[2][e]);
                const float y3 = dpp_xor1(W[3][e]);
                a[0  + e] = lo ? y1 : W[0][e];
                a[4  + e] = lo ? W[1][e] : y0;
                a[8  + e] = lo ? y3 : W[2][e];
                a[12 + e] = lo ? W[3][e] : y2;
            }

            // ---- prefetch next full tile into the freed ld regs ----
            if (t + 1 < TILES_PER_WAVE) {
                const long long r1 = r0 + 64;
                if (r1 + 64 <= (long long)nrows) {
                    const long long b4n = r1 * 4;
#pragma unroll
                    for (int c = 0; c < 4; ++c)
                        ld[c] = in4[b4n + (long long)(c * 64 + lane)];
                }
            }

            // ---- recursion (overlaps with the in-flight prefetch) ----
            levinson16(a);

            // ---- inverse quad transpose (same butterfly - involution) ----
#pragma unroll
            for (int e = 0; e < 4; ++e) {
                const float x0 = dpp_xor2(a[0  + e]);
                const float x1 = dpp_xor2(a[4  + e]);
                const float x2 = dpp_xor2(a[8  + e]);
                const float x3 = dpp_xor2(a[12 + e]);
                W[0][e] = hi ? x2 : a[0  + e];
                W[1][e] = hi ? x3 : a[4  + e];
                W[2][e] = hi ? a[8  + e] : x0;
                W[3][e] = hi ? a[12 + e] : x1;
            }
            f32x4 st[4];
#pragma unroll
            for (int e = 0; e < 4; ++e) {
                const float y0 = dpp_xor1(W[0][e]);
                const float y1 = dpp_xor1(W[1][e]);
                const float y2 = dpp_xor1(W[2][e]);
                const float y3 = dpp_xor1(W[3][e]);
                st[0][e] = lo ? y1 : W[0][e];
                st[1][e] = lo ? W[1][e] : y0;
                st[2][e] = lo ? y3 : W[2][e];
                st[3][e] = lo ? W[3][e] : y2;
            }

            // ---- coalesced stores (exact mirror of load distribution) ----
            const long long b4 = r0 * 4;
#pragma unroll
            for (int c = 0; c < 4; ++c)
                out4[b4 + (long long)(c * 64 + lane)] = st[c];
        } else {
            // ---- partial tile (last one only): per-lane guarded path ----
            const long long r = r0 + lane;
            if (r < (long long)nrows) {
                f32x4 v0 = in4[r * 4 + 0], v1 = in4[r * 4 + 1],
                      v2 = in4[r * 4 + 2], v3 = in4[r * 4 + 3];
                a[0]=v0.x; a[1]=v0.y; a[2]=v0.z; a[3]=v0.w;
                a[4]=v1.x; a[5]=v1.y; a[6]=v1.z; a[7]=v1.w;
                a[8]=v2.x; a[9]=v2.y; a[10]=v2.z; a[11]=v2.w;
                a[12]=v3.x; a[13]=v3.y; a[14]=v3.z; a[15]=v3.w;
                levinson16(a);
                v0.x=a[0]; v0.y=a[1]; v0.z=a[2]; v0.w=a[3];
                v1.x=a[4]; v1.y=a[5]; v1.z=a[6]; v1.w=a[7];
                v2.x=a[8]; v2.y=a[9]; v2.z=a[10]; v2.w=a[11];
                v3.x=a[12]; v3.y=a[13]; v3.z=a[14]; v3.w=a[15];
                out4[r * 4 + 0] = v0; out4[r * 4 + 1] = v1;
                out4[r * 4 + 2] = v2; out4[r * 4 + 3] = v3;
            }
            return;   // partial tile is always the last for this wave
        }
    }
}

extern "C" void kernel_launch(void* const* d_in, const int* in_sizes, int n_in,
                              void* d_out, int out_size, void* d_ws, size_t ws_size,
                              hipStream_t stream) {
    const float* x = (const float*)d_in[0];
    float* out = (float*)d_out;
    const int nrows = in_sizes[0] / N;                        // 2,097,152
    const int rows_per_wg = 64 * WAVES_PER_WG * TILES_PER_WAVE;  // 1024
    const int grid = (nrows + rows_per_wg - 1) / rows_per_wg;    // 2048
    lpc2rc_kernel<<<grid, 256, 0, stream>>>(x, out, nrows);
}